// Round 1
// baseline (1099.353 us; speedup 1.0000x reference)
//
#include <hip/hip_runtime.h>
#include <math.h>

constexpr int B_ = 64;
constexpr int N_ = 4096;
constexpr int D_ = 256;
constexpr int NCH = 64;            // score/partial chunks per batch row
constexpr int NPB = N_ / NCH;      // 64 n's per block
constexpr int NPW = NPB / 4;       // 16 n's per wave (4 waves/block)

// ---------------------------------------------------------------------------
// Check whether precision == I. flag=0 -> fast path (q = ||m||^2).
// Exactness for arbitrary precision is preserved via the slow path below.
// ---------------------------------------------------------------------------
__global__ __launch_bounds__(256) void flag_kernel(const float* __restrict__ P,
                                                   int* __restrict__ flag) {
    __shared__ int sh[256];
    const int tid = threadIdx.x;
    int bad = 0;
    for (int i = tid; i < D_ * D_; i += 256) {
        const int r = i >> 8, c = i & 255;
        const float expect = (r == c) ? 1.0f : 0.0f;
        bad |= (P[i] != expect) ? 1 : 0;
    }
    sh[tid] = bad;
    __syncthreads();
    for (int s = 128; s > 0; s >>= 1) {
        if (tid < s) sh[tid] |= sh[tid + s];
        __syncthreads();
    }
    if (tid == 0) *flag = sh[0];
}

// v = (P + P^T) z  — one block per b, thread = d. Tiny.
__global__ __launch_bounds__(256) void vcalc_kernel(const float* __restrict__ P,
                                                    const float* __restrict__ z,
                                                    float* __restrict__ v) {
    __shared__ float zsh[D_];
    const int b = blockIdx.x, d = threadIdx.x;
    zsh[d] = z[b * D_ + d];
    __syncthreads();
    float acc = 0.f;
    for (int e = 0; e < D_; e++)
        acc += (P[d * D_ + e] + P[e * D_ + d]) * zsh[e];
    v[b * D_ + d] = acc;
}

// ---------------------------------------------------------------------------
// Fused scores + online softmax + weighted-mean partials.
// One wave per n-row: lane l holds m[4l..4l+3] (float4, coalesced 1KB/row).
// s_n = 0.5*(v.m - m^T P m); running (max, sumexp, sum e^s * m) per wave,
// combined across the 4 waves -> one (M, S, T[256]) partial per (b, chunk).
// ---------------------------------------------------------------------------
__global__ __launch_bounds__(256) void fused_kernel(const float* __restrict__ means,
                                                    const float* __restrict__ v,
                                                    const float* __restrict__ P,
                                                    const int* __restrict__ flag,
                                                    float* __restrict__ Tbuf,
                                                    float2* __restrict__ stats) {
    const int b = blockIdx.y, chunk = blockIdx.x;
    const int tid = threadIdx.x, wave = tid >> 6, lane = tid & 63;
    __shared__ __align__(16) float vsh[D_];
    __shared__ __align__(16) float shbuf[4][D_];   // slow-path staging, then T combine
    __shared__ float wM[4], wS[4];
    vsh[tid] = v[b * D_ + tid];
    __syncthreads();
    const float4 v4 = ((const float4*)vsh)[lane];
    const int flg = *flag;

    float runM = -INFINITY, runS = 0.f;
    float4 t4 = make_float4(0.f, 0.f, 0.f, 0.f);
    const size_t base = ((size_t)b * N_ + (size_t)chunk * NPB + (size_t)wave * NPW) * D_;

    #pragma unroll 4
    for (int i = 0; i < NPW; i++) {
        const float4 m4 = ((const float4*)(means + base + (size_t)i * D_))[lane];
        float dot = m4.x * v4.x + m4.y * v4.y + m4.z * v4.z + m4.w * v4.w;
        float nrm = m4.x * m4.x + m4.y * m4.y + m4.z * m4.z + m4.w * m4.w;
        #pragma unroll
        for (int off = 1; off < 64; off <<= 1) {
            dot += __shfl_xor(dot, off, 64);
            nrm += __shfl_xor(nrm, off, 64);
        }
        float s = 0.5f * (dot - nrm);
        if (flg) {  // general-precision correction: replace ||m||^2 with m^T P m
            __syncthreads();
            ((float4*)shbuf[wave])[lane] = m4;
            __syncthreads();
            float c = 0.f;
            #pragma unroll
            for (int k = 0; k < 4; k++) {
                const int d = lane * 4 + k;
                float pm = 0.f;
                for (int e = 0; e < D_; e++) pm += P[d * D_ + e] * shbuf[wave][e];
                const float md = (k == 0) ? m4.x : (k == 1) ? m4.y : (k == 2) ? m4.z : m4.w;
                c += md * pm;
            }
            #pragma unroll
            for (int off = 1; off < 64; off <<= 1) c += __shfl_xor(c, off, 64);
            s += 0.5f * (nrm - c);
        }
        // online-softmax update (exp(-inf)==0 handles the first row)
        const float newM = fmaxf(runM, s);
        const float sc = __expf(runM - newM);
        const float e  = __expf(s - newM);
        runS = runS * sc + e;
        t4.x = fmaf(t4.x, sc, e * m4.x);
        t4.y = fmaf(t4.y, sc, e * m4.y);
        t4.z = fmaf(t4.z, sc, e * m4.z);
        t4.w = fmaf(t4.w, sc, e * m4.w);
        runM = newM;
    }

    __syncthreads();
    ((float4*)shbuf[wave])[lane] = t4;
    if (lane == 0) { wM[wave] = runM; wS[wave] = runS; }
    __syncthreads();
    const float M = fmaxf(fmaxf(wM[0], wM[1]), fmaxf(wM[2], wM[3]));
    const float a0 = __expf(wM[0] - M), a1 = __expf(wM[1] - M),
                a2 = __expf(wM[2] - M), a3 = __expf(wM[3] - M);
    const float Tc = a0 * shbuf[0][tid] + a1 * shbuf[1][tid] +
                     a2 * shbuf[2][tid] + a3 * shbuf[3][tid];
    Tbuf[((size_t)(b * NCH + chunk)) * D_ + tid] = Tc;
    if (tid == 0) {
        stats[b * NCH + chunk] =
            make_float2(M, a0 * wS[0] + a1 * wS[1] + a2 * wS[2] + a3 * wS[3]);
    }
}

// ---------------------------------------------------------------------------
// Combine chunk partials -> z_new (with global max rescale), then v=(P+P^T)z.
// Writes z to `out` on the final iteration.
// ---------------------------------------------------------------------------
__global__ __launch_bounds__(256) void combine_kernel(const float* __restrict__ Tbuf,
                                                      const float2* __restrict__ stats,
                                                      const float* __restrict__ P,
                                                      float* __restrict__ v,
                                                      float* __restrict__ out) {
    const int b = blockIdx.x, d = threadIdx.x;
    __shared__ float Msh[NCH], Ssh[NCH];
    __shared__ float zsh[D_];
    if (d < NCH) {
        const float2 st = stats[b * NCH + d];
        Msh[d] = st.x; Ssh[d] = st.y;
    }
    __syncthreads();
    float M = -INFINITY;
    for (int c = 0; c < NCH; c++) M = fmaxf(M, Msh[c]);
    float S = 0.f, acc = 0.f;
    for (int c = 0; c < NCH; c++) {
        const float a = __expf(Msh[c] - M);
        S += a * Ssh[c];
        acc += a * Tbuf[((size_t)(b * NCH + c)) * D_ + d];
    }
    const float z = acc / S;
    zsh[d] = z;
    if (out) out[b * D_ + d] = z;
    __syncthreads();
    float vv = 0.f;
    for (int e = 0; e < D_; e++)
        vv += (P[d * D_ + e] + P[e * D_ + d]) * zsh[e];
    v[b * D_ + d] = vv;
}

extern "C" void kernel_launch(void* const* d_in, const int* in_sizes, int n_in,
                              void* d_out, int out_size, void* d_ws, size_t ws_size,
                              hipStream_t stream) {
    // inputs: 0=x (unused by reference), 1=z, 2=means, 3=precision, 4=iterations(=10)
    const float* z0    = (const float*)d_in[1];
    const float* means = (const float*)d_in[2];
    const float* P     = (const float*)d_in[3];
    float* out = (float*)d_out;

    char* ws = (char*)d_ws;
    int*    flag  = (int*)ws;                                   // 4 B (pad to 256)
    float*  v     = (float*)(ws + 256);                         // B*D
    float*  Tbuf  = v + B_ * D_;                                // B*NCH*D (4 MB)
    float2* stats = (float2*)(Tbuf + (size_t)B_ * NCH * D_);    // B*NCH
    // total ws use ~= 4.3 MB

    flag_kernel<<<dim3(1), dim3(256), 0, stream>>>(P, flag);
    vcalc_kernel<<<dim3(B_), dim3(256), 0, stream>>>(P, z0, v);
    for (int t = 0; t < 10; t++) {
        fused_kernel<<<dim3(NCH, B_), dim3(256), 0, stream>>>(means, v, P, flag, Tbuf, stats);
        combine_kernel<<<dim3(B_), dim3(256), 0, stream>>>(Tbuf, stats, P, v,
                                                           (t == 9) ? out : nullptr);
    }
}

// Round 2
// 929.925 us; speedup vs baseline: 1.1822x; 1.1822x over previous
//
#include <hip/hip_runtime.h>
#include <math.h>

constexpr int B_ = 64;
constexpr int N_ = 4096;
constexpr int D_ = 256;
constexpr int NCH = 64;            // score/partial chunks per batch row
constexpr int NPB = N_ / NCH;      // 64 n's per block
constexpr int NPW = NPB / 4;       // 16 n's per wave (4 waves/block)

// ---------------------------------------------------------------------------
// Check whether precision == I. flag=0 -> fast paths everywhere.
// Exactness for arbitrary precision is preserved via the general paths.
// ---------------------------------------------------------------------------
__global__ __launch_bounds__(256) void flag_kernel(const float* __restrict__ P,
                                                   int* __restrict__ flag) {
    __shared__ int sh[256];
    const int tid = threadIdx.x;
    int bad = 0;
    for (int i = tid; i < D_ * D_; i += 256) {
        const int r = i >> 8, c = i & 255;
        const float expect = (r == c) ? 1.0f : 0.0f;
        bad |= (P[i] != expect) ? 1 : 0;
    }
    sh[tid] = bad;
    __syncthreads();
    for (int s = 128; s > 0; s >>= 1) {
        if (tid < s) sh[tid] |= sh[tid + s];
        __syncthreads();
    }
    if (tid == 0) *flag = sh[0];
}

// v = (P + P^T) z  — fast path v = 2z when P == I.
__global__ __launch_bounds__(256) void vcalc_kernel(const float* __restrict__ P,
                                                    const float* __restrict__ z,
                                                    const int* __restrict__ flag,
                                                    float* __restrict__ v) {
    __shared__ float zsh[D_];
    const int b = blockIdx.x, d = threadIdx.x;
    const float zd = z[b * D_ + d];
    if (*flag == 0) {
        v[b * D_ + d] = 2.0f * zd;
        return;
    }
    zsh[d] = zd;
    __syncthreads();
    float acc = 0.f;
    for (int e = 0; e < D_; e++)
        acc += (P[d * D_ + e] + P[e * D_ + d]) * zsh[e];
    v[b * D_ + d] = acc;
}

// ---------------------------------------------------------------------------
// Fused scores + online softmax + weighted-mean partials.
// One wave per n-row: lane l holds m[4l..4l+3] (float4, coalesced 1KB/row).
// P==I: s_n = 0.5 * sum_d m_d (v_d - m_d)  — ONE reduction chain per row.
// Running (max, sumexp, sum e^s * m) per wave; 4 waves combined per block.
// ---------------------------------------------------------------------------
__global__ __launch_bounds__(256) void fused_kernel(const float* __restrict__ means,
                                                    const float* __restrict__ v,
                                                    const float* __restrict__ P,
                                                    const int* __restrict__ flag,
                                                    float* __restrict__ Tbuf,
                                                    float2* __restrict__ stats) {
    const int b = blockIdx.y, chunk = blockIdx.x;
    const int tid = threadIdx.x, wave = tid >> 6, lane = tid & 63;
    __shared__ __align__(16) float vsh[D_];
    __shared__ __align__(16) float shbuf[4][D_];   // slow-path staging, then T combine
    __shared__ float wM[4], wS[4];
    vsh[tid] = v[b * D_ + tid];
    __syncthreads();
    const float4 v4 = ((const float4*)vsh)[lane];
    const int flg = *flag;

    float runM = -INFINITY, runS = 0.f;
    float4 t4 = make_float4(0.f, 0.f, 0.f, 0.f);
    const size_t base = ((size_t)b * N_ + (size_t)chunk * NPB + (size_t)wave * NPW) * D_;

    #pragma unroll 4
    for (int i = 0; i < NPW; i++) {
        const float4 m4 = ((const float4*)(means + base + (size_t)i * D_))[lane];
        // p = sum_d m_d * (v_d - m_d)   (single reduction chain)
        float p = m4.x * (v4.x - m4.x) + m4.y * (v4.y - m4.y) +
                  m4.z * (v4.z - m4.z) + m4.w * (v4.w - m4.w);
        #pragma unroll
        for (int off = 1; off < 64; off <<= 1) p += __shfl_xor(p, off, 64);
        float s = 0.5f * p;
        if (flg) {  // general precision: s = 0.5*(v.m - m^T P m)
            float nrm = m4.x * m4.x + m4.y * m4.y + m4.z * m4.z + m4.w * m4.w;
            __syncthreads();
            ((float4*)shbuf[wave])[lane] = m4;
            __syncthreads();
            float c = 0.f;
            #pragma unroll
            for (int k = 0; k < 4; k++) {
                const int d = lane * 4 + k;
                float pm = 0.f;
                for (int e = 0; e < D_; e++) pm += P[d * D_ + e] * shbuf[wave][e];
                const float md = (k == 0) ? m4.x : (k == 1) ? m4.y : (k == 2) ? m4.z : m4.w;
                c += md * pm;
            }
            #pragma unroll
            for (int off = 1; off < 64; off <<= 1) {
                c += __shfl_xor(c, off, 64);
                nrm += __shfl_xor(nrm, off, 64);
            }
            s += 0.5f * (nrm - c);
        }
        // online-softmax update (exp(-inf)==0 handles the first row)
        const float newM = fmaxf(runM, s);
        const float sc = __expf(runM - newM);
        const float e  = __expf(s - newM);
        runS = runS * sc + e;
        t4.x = fmaf(t4.x, sc, e * m4.x);
        t4.y = fmaf(t4.y, sc, e * m4.y);
        t4.z = fmaf(t4.z, sc, e * m4.z);
        t4.w = fmaf(t4.w, sc, e * m4.w);
        runM = newM;
    }

    __syncthreads();
    ((float4*)shbuf[wave])[lane] = t4;
    if (lane == 0) { wM[wave] = runM; wS[wave] = runS; }
    __syncthreads();
    const float M = fmaxf(fmaxf(wM[0], wM[1]), fmaxf(wM[2], wM[3]));
    const float a0 = __expf(wM[0] - M), a1 = __expf(wM[1] - M),
                a2 = __expf(wM[2] - M), a3 = __expf(wM[3] - M);
    const float Tc = a0 * shbuf[0][tid] + a1 * shbuf[1][tid] +
                     a2 * shbuf[2][tid] + a3 * shbuf[3][tid];
    Tbuf[((size_t)(b * NCH + chunk)) * D_ + tid] = Tc;
    if (tid == 0) {
        stats[b * NCH + chunk] =
            make_float2(M, a0 * wS[0] + a1 * wS[1] + a2 * wS[2] + a3 * wS[3]);
    }
}

// ---------------------------------------------------------------------------
// Combine chunk partials -> z_new (global max rescale), then v for next iter.
// P==I fast path: v = 2z (no matvec). Writes z to `out` on final iteration.
// ---------------------------------------------------------------------------
__global__ __launch_bounds__(256) void combine_kernel(const float* __restrict__ Tbuf,
                                                      const float2* __restrict__ stats,
                                                      const float* __restrict__ P,
                                                      const int* __restrict__ flag,
                                                      float* __restrict__ v,
                                                      float* __restrict__ out) {
    const int b = blockIdx.x, d = threadIdx.x;
    __shared__ float Msh[NCH], Ssh[NCH];
    __shared__ float zsh[D_];
    if (d < NCH) {
        const float2 st = stats[b * NCH + d];
        Msh[d] = st.x; Ssh[d] = st.y;
    }
    __syncthreads();
    float M = -INFINITY;
    for (int c = 0; c < NCH; c++) M = fmaxf(M, Msh[c]);
    float S = 0.f, acc = 0.f;
    for (int c = 0; c < NCH; c++) {
        const float a = __expf(Msh[c] - M);
        S += a * Ssh[c];
        acc += a * Tbuf[((size_t)(b * NCH + c)) * D_ + d];
    }
    const float z = acc / S;
    if (out) out[b * D_ + d] = z;
    if (*flag == 0) {
        v[b * D_ + d] = 2.0f * z;
        return;
    }
    zsh[d] = z;
    __syncthreads();
    float vv = 0.f;
    for (int e = 0; e < D_; e++)
        vv += (P[d * D_ + e] + P[e * D_ + d]) * zsh[e];
    v[b * D_ + d] = vv;
}

extern "C" void kernel_launch(void* const* d_in, const int* in_sizes, int n_in,
                              void* d_out, int out_size, void* d_ws, size_t ws_size,
                              hipStream_t stream) {
    // inputs: 0=x (unused by reference), 1=z, 2=means, 3=precision, 4=iterations(=10)
    const float* z0    = (const float*)d_in[1];
    const float* means = (const float*)d_in[2];
    const float* P     = (const float*)d_in[3];
    float* out = (float*)d_out;

    char* ws = (char*)d_ws;
    int*    flag  = (int*)ws;                                   // 4 B (pad to 256)
    float*  v     = (float*)(ws + 256);                         // B*D
    float*  Tbuf  = v + B_ * D_;                                // B*NCH*D (4 MB)
    float2* stats = (float2*)(Tbuf + (size_t)B_ * NCH * D_);    // B*NCH

    flag_kernel<<<dim3(1), dim3(256), 0, stream>>>(P, flag);
    vcalc_kernel<<<dim3(B_), dim3(256), 0, stream>>>(P, z0, flag, v);
    for (int t = 0; t < 10; t++) {
        fused_kernel<<<dim3(NCH, B_), dim3(256), 0, stream>>>(means, v, P, flag, Tbuf, stats);
        combine_kernel<<<dim3(B_), dim3(256), 0, stream>>>(Tbuf, stats, P, flag, v,
                                                           (t == 9) ? out : nullptr);
    }
}

// Round 3
// 835.910 us; speedup vs baseline: 1.3152x; 1.1125x over previous
//
#include <hip/hip_runtime.h>
#include <math.h>

constexpr int B_ = 64;
constexpr int N_ = 4096;
constexpr int D_ = 256;
constexpr int NCH = 64;            // score/partial chunks per batch row
constexpr int NPB = N_ / NCH;      // 64 n's per block
constexpr int NPW = NPB / 4;       // 16 n's per wave (4 waves/block)
constexpr int NG  = NPW / 4;       // 4 groups of 4 rows per wave

// ---------------------------------------------------------------------------
// Check whether precision == I. flag=0 -> fast paths everywhere.
// ---------------------------------------------------------------------------
__global__ __launch_bounds__(256) void flag_kernel(const float* __restrict__ P,
                                                   int* __restrict__ flag) {
    __shared__ int sh[256];
    const int tid = threadIdx.x;
    int bad = 0;
    for (int i = tid; i < D_ * D_; i += 256) {
        const int r = i >> 8, c = i & 255;
        const float expect = (r == c) ? 1.0f : 0.0f;
        bad |= (P[i] != expect) ? 1 : 0;
    }
    sh[tid] = bad;
    __syncthreads();
    for (int s = 128; s > 0; s >>= 1) {
        if (tid < s) sh[tid] |= sh[tid + s];
        __syncthreads();
    }
    if (tid == 0) *flag = sh[0];
}

// v = (P + P^T) z  — fast path v = 2z when P == I.
__global__ __launch_bounds__(256) void vcalc_kernel(const float* __restrict__ P,
                                                    const float* __restrict__ z,
                                                    const int* __restrict__ flag,
                                                    float* __restrict__ v) {
    __shared__ float zsh[D_];
    const int b = blockIdx.x, d = threadIdx.x;
    const float zd = z[b * D_ + d];
    if (*flag == 0) {
        v[b * D_ + d] = 2.0f * zd;
        return;
    }
    zsh[d] = zd;
    __syncthreads();
    float acc = 0.f;
    for (int e = 0; e < D_; e++)
        acc += (P[d * D_ + e] + P[e * D_ + d]) * zsh[e];
    v[b * D_ + d] = acc;
}

// ---------------------------------------------------------------------------
// Fused scores + online softmax + weighted-mean partials, 4-row ILP.
// One wave handles 16 rows as 4 groups of 4: 4 independent loads, 4
// interleaved butterfly reductions, ONE online-softmax update per group.
// ---------------------------------------------------------------------------
__global__ __launch_bounds__(256) void fused_kernel(const float* __restrict__ means,
                                                    const float* __restrict__ v,
                                                    const float* __restrict__ P,
                                                    const int* __restrict__ flag,
                                                    float* __restrict__ Tbuf,
                                                    float2* __restrict__ stats) {
    const int b = blockIdx.y, chunk = blockIdx.x;
    const int tid = threadIdx.x, wave = tid >> 6, lane = tid & 63;
    __shared__ __align__(16) float vsh[D_];
    __shared__ __align__(16) float shbuf[4][D_];   // slow-path staging, then T combine
    __shared__ float wM[4], wS[4];
    vsh[tid] = v[b * D_ + tid];
    __syncthreads();
    const float4 v4 = ((const float4*)vsh)[lane];
    const int flg = *flag;

    float runM = -INFINITY, runS = 0.f;
    float4 t4 = make_float4(0.f, 0.f, 0.f, 0.f);
    const size_t base = ((size_t)b * N_ + (size_t)chunk * NPB + (size_t)wave * NPW) * D_;

    for (int g = 0; g < NG; g++) {
        const float* rp = means + base + (size_t)(g * 4) * D_;
        const float4 m0 = ((const float4*)(rp + 0 * D_))[lane];
        const float4 m1 = ((const float4*)(rp + 1 * D_))[lane];
        const float4 m2 = ((const float4*)(rp + 2 * D_))[lane];
        const float4 m3 = ((const float4*)(rp + 3 * D_))[lane];
        // p_j = sum_d m_d * (v_d - m_d), four independent chains
        float p0 = m0.x*(v4.x-m0.x) + m0.y*(v4.y-m0.y) + m0.z*(v4.z-m0.z) + m0.w*(v4.w-m0.w);
        float p1 = m1.x*(v4.x-m1.x) + m1.y*(v4.y-m1.y) + m1.z*(v4.z-m1.z) + m1.w*(v4.w-m1.w);
        float p2 = m2.x*(v4.x-m2.x) + m2.y*(v4.y-m2.y) + m2.z*(v4.z-m2.z) + m2.w*(v4.w-m2.w);
        float p3 = m3.x*(v4.x-m3.x) + m3.y*(v4.y-m3.y) + m3.z*(v4.z-m3.z) + m3.w*(v4.w-m3.w);
        #pragma unroll
        for (int off = 1; off < 64; off <<= 1) {
            p0 += __shfl_xor(p0, off, 64);
            p1 += __shfl_xor(p1, off, 64);
            p2 += __shfl_xor(p2, off, 64);
            p3 += __shfl_xor(p3, off, 64);
        }
        float s0 = 0.5f * p0, s1 = 0.5f * p1, s2 = 0.5f * p2, s3 = 0.5f * p3;

        if (flg) {  // general precision: s_j += 0.5*(||m||^2 - m^T P m)
            #pragma unroll
            for (int j = 0; j < 4; j++) {
                const float4 mj = (j == 0) ? m0 : (j == 1) ? m1 : (j == 2) ? m2 : m3;
                float nrm = mj.x*mj.x + mj.y*mj.y + mj.z*mj.z + mj.w*mj.w;
                __syncthreads();
                ((float4*)shbuf[wave])[lane] = mj;
                __syncthreads();
                float c = 0.f;
                #pragma unroll
                for (int k = 0; k < 4; k++) {
                    const int d = lane * 4 + k;
                    float pm = 0.f;
                    for (int e = 0; e < D_; e++) pm += P[d * D_ + e] * shbuf[wave][e];
                    const float md = (k==0)?mj.x:(k==1)?mj.y:(k==2)?mj.z:mj.w;
                    c += md * pm;
                }
                #pragma unroll
                for (int off = 1; off < 64; off <<= 1) {
                    c   += __shfl_xor(c, off, 64);
                    nrm += __shfl_xor(nrm, off, 64);
                }
                const float corr = 0.5f * (nrm - c);
                if (j == 0) s0 += corr; else if (j == 1) s1 += corr;
                else if (j == 2) s2 += corr; else s3 += corr;
            }
        }

        // one online-softmax update for 4 rows (exp(-inf)==0 handles startup)
        const float mx   = fmaxf(fmaxf(s0, s1), fmaxf(s2, s3));
        const float newM = fmaxf(runM, mx);
        const float sc = __expf(runM - newM);
        const float e0 = __expf(s0 - newM), e1 = __expf(s1 - newM);
        const float e2 = __expf(s2 - newM), e3 = __expf(s3 - newM);
        runS = fmaf(runS, sc, (e0 + e1) + (e2 + e3));
        t4.x = fmaf(t4.x, sc, fmaf(e0, m0.x, fmaf(e1, m1.x, fmaf(e2, m2.x, e3 * m3.x))));
        t4.y = fmaf(t4.y, sc, fmaf(e0, m0.y, fmaf(e1, m1.y, fmaf(e2, m2.y, e3 * m3.y))));
        t4.z = fmaf(t4.z, sc, fmaf(e0, m0.z, fmaf(e1, m1.z, fmaf(e2, m2.z, e3 * m3.z))));
        t4.w = fmaf(t4.w, sc, fmaf(e0, m0.w, fmaf(e1, m1.w, fmaf(e2, m2.w, e3 * m3.w))));
        runM = newM;
    }

    __syncthreads();
    ((float4*)shbuf[wave])[lane] = t4;
    if (lane == 0) { wM[wave] = runM; wS[wave] = runS; }
    __syncthreads();
    const float M = fmaxf(fmaxf(wM[0], wM[1]), fmaxf(wM[2], wM[3]));
    const float a0 = __expf(wM[0] - M), a1 = __expf(wM[1] - M),
                a2 = __expf(wM[2] - M), a3 = __expf(wM[3] - M);
    const float Tc = a0 * shbuf[0][tid] + a1 * shbuf[1][tid] +
                     a2 * shbuf[2][tid] + a3 * shbuf[3][tid];
    Tbuf[((size_t)(b * NCH + chunk)) * D_ + tid] = Tc;
    if (tid == 0) {
        stats[b * NCH + chunk] =
            make_float2(M, a0 * wS[0] + a1 * wS[1] + a2 * wS[2] + a3 * wS[3]);
    }
}

// ---------------------------------------------------------------------------
// Combine chunk partials -> z_new (global max rescale), then v for next iter.
// ---------------------------------------------------------------------------
__global__ __launch_bounds__(256) void combine_kernel(const float* __restrict__ Tbuf,
                                                      const float2* __restrict__ stats,
                                                      const float* __restrict__ P,
                                                      const int* __restrict__ flag,
                                                      float* __restrict__ v,
                                                      float* __restrict__ out) {
    const int b = blockIdx.x, d = threadIdx.x;
    __shared__ float Msh[NCH], Ssh[NCH];
    __shared__ float zsh[D_];
    if (d < NCH) {
        const float2 st = stats[b * NCH + d];
        Msh[d] = st.x; Ssh[d] = st.y;
    }
    __syncthreads();
    float M = -INFINITY;
    for (int c = 0; c < NCH; c++) M = fmaxf(M, Msh[c]);
    float S = 0.f, acc = 0.f;
    for (int c = 0; c < NCH; c++) {
        const float a = __expf(Msh[c] - M);
        S += a * Ssh[c];
        acc += a * Tbuf[((size_t)(b * NCH + c)) * D_ + d];
    }
    const float z = acc / S;
    if (out) out[b * D_ + d] = z;
    if (*flag == 0) {
        v[b * D_ + d] = 2.0f * z;
        return;
    }
    zsh[d] = z;
    __syncthreads();
    float vv = 0.f;
    for (int e = 0; e < D_; e++)
        vv += (P[d * D_ + e] + P[e * D_ + d]) * zsh[e];
    v[b * D_ + d] = vv;
}

extern "C" void kernel_launch(void* const* d_in, const int* in_sizes, int n_in,
                              void* d_out, int out_size, void* d_ws, size_t ws_size,
                              hipStream_t stream) {
    // inputs: 0=x (unused by reference), 1=z, 2=means, 3=precision, 4=iterations(=10)
    const float* z0    = (const float*)d_in[1];
    const float* means = (const float*)d_in[2];
    const float* P     = (const float*)d_in[3];
    float* out = (float*)d_out;

    char* ws = (char*)d_ws;
    int*    flag  = (int*)ws;                                   // 4 B (pad to 256)
    float*  v     = (float*)(ws + 256);                         // B*D
    float*  Tbuf  = v + B_ * D_;                                // B*NCH*D (4 MB)
    float2* stats = (float2*)(Tbuf + (size_t)B_ * NCH * D_);    // B*NCH

    flag_kernel<<<dim3(1), dim3(256), 0, stream>>>(P, flag);
    vcalc_kernel<<<dim3(B_), dim3(256), 0, stream>>>(P, z0, flag, v);
    for (int t = 0; t < 10; t++) {
        fused_kernel<<<dim3(NCH, B_), dim3(256), 0, stream>>>(means, v, P, flag, Tbuf, stats);
        combine_kernel<<<dim3(B_), dim3(256), 0, stream>>>(Tbuf, stats, P, flag, v,
                                                           (t == 9) ? out : nullptr);
    }
}

// Round 4
// 732.714 us; speedup vs baseline: 1.5004x; 1.1408x over previous
//
#include <hip/hip_runtime.h>
#include <hip/hip_fp16.h>
#include <math.h>

constexpr int B_ = 64;
constexpr int N_ = 4096;
constexpr int D_ = 256;
constexpr int NCH = 64;            // chunks per batch row
constexpr int NPB = N_ / NCH;      // 64 rows per block
constexpr int NPW = NPB / 4;       // 16 rows per wave
constexpr int NSTEP = NPW / 4;     // 4 steps; each step = 4 rows (one per 16-lane group)

// ---------------------------------------------------------------------------
// Check whether precision == I. flag=0 -> fast paths everywhere.
// ---------------------------------------------------------------------------
__global__ __launch_bounds__(256) void flag_kernel(const float* __restrict__ P,
                                                   int* __restrict__ flag) {
    __shared__ int sh[256];
    const int tid = threadIdx.x;
    int bad = 0;
    for (int i = tid; i < D_ * D_; i += 256) {
        const int r = i >> 8, c = i & 255;
        const float expect = (r == c) ? 1.0f : 0.0f;
        bad |= (P[i] != expect) ? 1 : 0;
    }
    sh[tid] = bad;
    __syncthreads();
    for (int s = 128; s > 0; s >>= 1) {
        if (tid < s) sh[tid] |= sh[tid + s];
        __syncthreads();
    }
    if (tid == 0) *flag = sh[0];
}

// v = (P + P^T) z  — fast path v = 2z when P == I.
__global__ __launch_bounds__(256) void vcalc_kernel(const float* __restrict__ P,
                                                    const float* __restrict__ z,
                                                    const int* __restrict__ flag,
                                                    float* __restrict__ v) {
    __shared__ float zsh[D_];
    const int b = blockIdx.x, d = threadIdx.x;
    const float zd = z[b * D_ + d];
    if (*flag == 0) {
        v[b * D_ + d] = 2.0f * zd;
        return;
    }
    zsh[d] = zd;
    __syncthreads();
    float acc = 0.f;
    for (int e = 0; e < D_; e++)
        acc += (P[d * D_ + e] + P[e * D_ + d]) * zsh[e];
    v[b * D_ + d] = acc;
}

// ---------------------------------------------------------------------------
// Shared epilogue: combine 4 lane-groups (xor 16/32), then 4 waves via LDS.
// t[] holds 16 components per lane; FID(j) gives the float4 index into a
// 256-float d-vector for fragment j of this lane.
// ---------------------------------------------------------------------------
#define EPILOGUE(FIDX)                                                          \
    {                                                                           \
        float Mw = runM;                                                        \
        Mw = fmaxf(Mw, __shfl_xor(Mw, 16, 64));                                 \
        Mw = fmaxf(Mw, __shfl_xor(Mw, 32, 64));                                 \
        const float a = __expf(runM - Mw);                                      \
        float Sa = runS * a;                                                    \
        Sa += __shfl_xor(Sa, 16, 64);                                           \
        Sa += __shfl_xor(Sa, 32, 64);                                           \
        _Pragma("unroll")                                                       \
        for (int j = 0; j < 4; j++) {                                           \
            t[j].x *= a; t[j].y *= a; t[j].z *= a; t[j].w *= a;                 \
            t[j].x += __shfl_xor(t[j].x, 16, 64);                               \
            t[j].y += __shfl_xor(t[j].y, 16, 64);                               \
            t[j].z += __shfl_xor(t[j].z, 16, 64);                               \
            t[j].w += __shfl_xor(t[j].w, 16, 64);                               \
            t[j].x += __shfl_xor(t[j].x, 32, 64);                               \
            t[j].y += __shfl_xor(t[j].y, 32, 64);                               \
            t[j].z += __shfl_xor(t[j].z, 32, 64);                               \
            t[j].w += __shfl_xor(t[j].w, 32, 64);                               \
        }                                                                       \
        if (lane < 16) {                                                        \
            _Pragma("unroll")                                                   \
            for (int j = 0; j < 4; j++)                                         \
                ((float4*)shbuf[wave])[FIDX(j)] = t[j];                         \
        }                                                                       \
        if (lane == 0) { wM[wave] = Mw; wS[wave] = Sa; }                        \
        __syncthreads();                                                        \
        const float M = fmaxf(fmaxf(wM[0], wM[1]), fmaxf(wM[2], wM[3]));        \
        const float a0 = __expf(wM[0] - M), a1 = __expf(wM[1] - M),             \
                    a2 = __expf(wM[2] - M), a3 = __expf(wM[3] - M);             \
        const float Tc = a0 * shbuf[0][tid] + a1 * shbuf[1][tid] +              \
                         a2 * shbuf[2][tid] + a3 * shbuf[3][tid];               \
        Tbuf[((size_t)(b * NCH + chunk)) * D_ + tid] = Tc;                      \
        if (tid == 0)                                                           \
            stats[b * NCH + chunk] =                                            \
                make_float2(M, a0 * wS[0] + a1 * wS[1] + a2 * wS[2] + a3 * wS[3]); \
    }

// ---------------------------------------------------------------------------
// fp32 fused kernel (optionally emits fp16 copy of means for later iterations).
// Lane-group layout: lane l handles 16 elems of row (l>>4): d = (l&15)*4+64j.
// ---------------------------------------------------------------------------
template <bool WRITE_H>
__global__ __launch_bounds__(256) void fused_f32_kernel(const float* __restrict__ means,
                                                        const float* __restrict__ v,
                                                        const float* __restrict__ P,
                                                        const int* __restrict__ flag,
                                                        __half* __restrict__ mh,
                                                        float* __restrict__ Tbuf,
                                                        float2* __restrict__ stats) {
    const int b = blockIdx.y, chunk = blockIdx.x;
    const int tid = threadIdx.x, wave = tid >> 6, lane = tid & 63;
    const int q = lane & 15, g = lane >> 4;
    __shared__ __align__(16) float vsh[D_];
    __shared__ __align__(16) float shbuf[4][D_];
    __shared__ __align__(16) float srows[4][4][D_];   // slow-path staging only
    __shared__ float wM[4], wS[4];
    vsh[tid] = v[b * D_ + tid];
    __syncthreads();
    float4 vr[4];
    #pragma unroll
    for (int j = 0; j < 4; j++) vr[j] = ((const float4*)vsh)[q + 16 * j];
    const int flg = *flag;

    float runM = -INFINITY, runS = 0.f;
    float4 t[4];
    #pragma unroll
    for (int j = 0; j < 4; j++) t[j] = make_float4(0.f, 0.f, 0.f, 0.f);

    const size_t rowbase = (size_t)b * N_ + (size_t)chunk * NPB + (size_t)wave * NPW;

    for (int step = 0; step < NSTEP; step++) {
        const int r = step * 4 + g;
        const float* rp = means + (rowbase + r) * D_;
        float4 m[4];
        #pragma unroll
        for (int j = 0; j < 4; j++) m[j] = ((const float4*)rp)[q + 16 * j];
        if (WRITE_H) {
            __half* hp = mh + (rowbase + r) * D_;
            #pragma unroll
            for (int j = 0; j < 4; j++) {
                union { uint2 u; __half2 h[2]; } pk;
                pk.h[0] = __floats2half2_rn(m[j].x, m[j].y);
                pk.h[1] = __floats2half2_rn(m[j].z, m[j].w);
                *(uint2*)(hp + q * 4 + 64 * j) = pk.u;
            }
        }
        float p = 0.f;
        #pragma unroll
        for (int j = 0; j < 4; j++) {
            p += m[j].x * (vr[j].x - m[j].x);
            p += m[j].y * (vr[j].y - m[j].y);
            p += m[j].z * (vr[j].z - m[j].z);
            p += m[j].w * (vr[j].w - m[j].w);
        }
        p += __shfl_xor(p, 1, 64);
        p += __shfl_xor(p, 2, 64);
        p += __shfl_xor(p, 4, 64);
        p += __shfl_xor(p, 8, 64);
        float s = 0.5f * p;
        if (flg) {  // general precision: s += 0.5*(||m||^2 - m^T P m)
            __syncthreads();
            #pragma unroll
            for (int j = 0; j < 4; j++) ((float4*)&srows[wave][g][64 * j])[q] = m[j];
            __syncthreads();
            float dl = 0.f;
            for (int k = 0; k < 16; k++) {
                const int d = q * 16 + k;
                const float md = srows[wave][g][d];
                float pm = 0.f;
                for (int e = 0; e < D_; e++) pm += P[d * D_ + e] * srows[wave][g][e];
                dl += md * (md - pm);
            }
            dl += __shfl_xor(dl, 1, 64);
            dl += __shfl_xor(dl, 2, 64);
            dl += __shfl_xor(dl, 4, 64);
            dl += __shfl_xor(dl, 8, 64);
            s += 0.5f * dl;
        }
        const float newM = fmaxf(runM, s);
        const float sc = __expf(runM - newM);
        const float e  = __expf(s - newM);
        runS = fmaf(runS, sc, e);
        #pragma unroll
        for (int j = 0; j < 4; j++) {
            t[j].x = fmaf(t[j].x, sc, e * m[j].x);
            t[j].y = fmaf(t[j].y, sc, e * m[j].y);
            t[j].z = fmaf(t[j].z, sc, e * m[j].z);
            t[j].w = fmaf(t[j].w, sc, e * m[j].w);
        }
        runM = newM;
    }
    #define FIDX_F32(j) (q + 16 * (j))
    EPILOGUE(FIDX_F32)
}

// ---------------------------------------------------------------------------
// fp16 fused kernel: reads the fp16 means copy (iterations 1..9).
// Lane l handles 16 elems of row (l>>4): d = (l&15)*8 + 128*jj + 4*h + k.
// ---------------------------------------------------------------------------
__global__ __launch_bounds__(256) void fused_f16_kernel(const __half* __restrict__ mh,
                                                        const float* __restrict__ v,
                                                        const float* __restrict__ P,
                                                        const int* __restrict__ flag,
                                                        float* __restrict__ Tbuf,
                                                        float2* __restrict__ stats) {
    const int b = blockIdx.y, chunk = blockIdx.x;
    const int tid = threadIdx.x, wave = tid >> 6, lane = tid & 63;
    const int q = lane & 15, g = lane >> 4;
    __shared__ __align__(16) float vsh[D_];
    __shared__ __align__(16) float shbuf[4][D_];
    __shared__ __align__(16) float srows[4][4][D_];   // slow-path staging only
    __shared__ float wM[4], wS[4];
    vsh[tid] = v[b * D_ + tid];
    __syncthreads();
    float4 vr[4];   // vr[jj*2+h] covers d = q*8 + 128*jj + 4*h
    #pragma unroll
    for (int jj = 0; jj < 2; jj++)
        #pragma unroll
        for (int h = 0; h < 2; h++)
            vr[jj * 2 + h] = ((const float4*)vsh)[q * 2 + 32 * jj + h];
    const int flg = *flag;

    float runM = -INFINITY, runS = 0.f;
    float4 t[4];
    #pragma unroll
    for (int j = 0; j < 4; j++) t[j] = make_float4(0.f, 0.f, 0.f, 0.f);

    const size_t rowbase = (size_t)b * N_ + (size_t)chunk * NPB + (size_t)wave * NPW;

    for (int step = 0; step < NSTEP; step++) {
        const int r = step * 4 + g;
        const __half* rp = mh + (rowbase + r) * D_;
        float4 m[4];
        #pragma unroll
        for (int jj = 0; jj < 2; jj++) {
            float4 raw = ((const float4*)rp)[q + 16 * jj];   // 8 halves
            const __half2* hp2 = (const __half2*)&raw;
            const float2 f0 = __half22float2(hp2[0]);
            const float2 f1 = __half22float2(hp2[1]);
            const float2 f2 = __half22float2(hp2[2]);
            const float2 f3 = __half22float2(hp2[3]);
            m[jj * 2 + 0] = make_float4(f0.x, f0.y, f1.x, f1.y);
            m[jj * 2 + 1] = make_float4(f2.x, f2.y, f3.x, f3.y);
        }
        float p = 0.f;
        #pragma unroll
        for (int j = 0; j < 4; j++) {
            p += m[j].x * (vr[j].x - m[j].x);
            p += m[j].y * (vr[j].y - m[j].y);
            p += m[j].z * (vr[j].z - m[j].z);
            p += m[j].w * (vr[j].w - m[j].w);
        }
        p += __shfl_xor(p, 1, 64);
        p += __shfl_xor(p, 2, 64);
        p += __shfl_xor(p, 4, 64);
        p += __shfl_xor(p, 8, 64);
        float s = 0.5f * p;
        if (flg) {  // general precision on the quantized means
            __syncthreads();
            #pragma unroll
            for (int jj = 0; jj < 2; jj++)
                #pragma unroll
                for (int h = 0; h < 2; h++)
                    ((float4*)&srows[wave][g][0])[q * 2 + 32 * jj + h] = m[jj * 2 + h];
            __syncthreads();
            float dl = 0.f;
            for (int k = 0; k < 16; k++) {
                const int d = q * 16 + k;
                const float md = srows[wave][g][d];
                float pm = 0.f;
                for (int e = 0; e < D_; e++) pm += P[d * D_ + e] * srows[wave][g][e];
                dl += md * (md - pm);
            }
            dl += __shfl_xor(dl, 1, 64);
            dl += __shfl_xor(dl, 2, 64);
            dl += __shfl_xor(dl, 4, 64);
            dl += __shfl_xor(dl, 8, 64);
            s += 0.5f * dl;
        }
        const float newM = fmaxf(runM, s);
        const float sc = __expf(runM - newM);
        const float e  = __expf(s - newM);
        runS = fmaf(runS, sc, e);
        #pragma unroll
        for (int j = 0; j < 4; j++) {
            t[j].x = fmaf(t[j].x, sc, e * m[j].x);
            t[j].y = fmaf(t[j].y, sc, e * m[j].y);
            t[j].z = fmaf(t[j].z, sc, e * m[j].z);
            t[j].w = fmaf(t[j].w, sc, e * m[j].w);
        }
        runM = newM;
    }
    #define FIDX_F16(j) (q * 2 + 32 * ((j) >> 1) + ((j) & 1))
    EPILOGUE(FIDX_F16)
}

// ---------------------------------------------------------------------------
// Combine chunk partials -> z_new (global max rescale), then v for next iter.
// ---------------------------------------------------------------------------
__global__ __launch_bounds__(256) void combine_kernel(const float* __restrict__ Tbuf,
                                                      const float2* __restrict__ stats,
                                                      const float* __restrict__ P,
                                                      const int* __restrict__ flag,
                                                      float* __restrict__ v,
                                                      float* __restrict__ out) {
    const int b = blockIdx.x, d = threadIdx.x;
    __shared__ float Msh[NCH], Ssh[NCH];
    __shared__ float zsh[D_];
    if (d < NCH) {
        const float2 st = stats[b * NCH + d];
        Msh[d] = st.x; Ssh[d] = st.y;
    }
    __syncthreads();
    float M = -INFINITY;
    for (int c = 0; c < NCH; c++) M = fmaxf(M, Msh[c]);
    float S = 0.f, acc = 0.f;
    for (int c = 0; c < NCH; c++) {
        const float a = __expf(Msh[c] - M);
        S += a * Ssh[c];
        acc += a * Tbuf[((size_t)(b * NCH + c)) * D_ + d];
    }
    const float z = acc / S;
    if (out) out[b * D_ + d] = z;
    if (*flag == 0) {
        v[b * D_ + d] = 2.0f * z;
        return;
    }
    zsh[d] = z;
    __syncthreads();
    float vv = 0.f;
    for (int e = 0; e < D_; e++)
        vv += (P[d * D_ + e] + P[e * D_ + d]) * zsh[e];
    v[b * D_ + d] = vv;
}

extern "C" void kernel_launch(void* const* d_in, const int* in_sizes, int n_in,
                              void* d_out, int out_size, void* d_ws, size_t ws_size,
                              hipStream_t stream) {
    // inputs: 0=x (unused by reference), 1=z, 2=means, 3=precision, 4=iterations(=10)
    const float* z0    = (const float*)d_in[1];
    const float* means = (const float*)d_in[2];
    const float* P     = (const float*)d_in[3];
    float* out = (float*)d_out;

    char* ws = (char*)d_ws;
    int*    flag  = (int*)ws;                                   // 4 B (pad to 256)
    float*  v     = (float*)(ws + 256);                         // B*D
    float*  Tbuf  = v + B_ * D_;                                // B*NCH*D (4 MB)
    float2* stats = (float2*)(Tbuf + (size_t)B_ * NCH * D_);    // B*NCH

    size_t used = 256 + (size_t)B_ * D_ * 4 + (size_t)B_ * NCH * D_ * 4 +
                  (size_t)B_ * NCH * 8;
    used = (used + 255) & ~(size_t)255;
    const size_t need_h = (size_t)B_ * N_ * D_ * sizeof(__half);   // 128 MiB
    const bool use_h = (ws_size >= used + need_h);
    __half* mh = (__half*)(ws + used);

    flag_kernel<<<dim3(1), dim3(256), 0, stream>>>(P, flag);
    vcalc_kernel<<<dim3(B_), dim3(256), 0, stream>>>(P, z0, flag, v);
    if (use_h) {
        // iteration 0: fp32 read + emit fp16 copy; iterations 1..9: fp16 read
        fused_f32_kernel<true><<<dim3(NCH, B_), dim3(256), 0, stream>>>(
            means, v, P, flag, mh, Tbuf, stats);
        combine_kernel<<<dim3(B_), dim3(256), 0, stream>>>(Tbuf, stats, P, flag, v, nullptr);
        for (int t = 1; t < 10; t++) {
            fused_f16_kernel<<<dim3(NCH, B_), dim3(256), 0, stream>>>(
                mh, v, P, flag, Tbuf, stats);
            combine_kernel<<<dim3(B_), dim3(256), 0, stream>>>(Tbuf, stats, P, flag, v,
                                                               (t == 9) ? out : nullptr);
        }
    } else {
        for (int t = 0; t < 10; t++) {
            fused_f32_kernel<false><<<dim3(NCH, B_), dim3(256), 0, stream>>>(
                means, v, P, flag, nullptr, Tbuf, stats);
            combine_kernel<<<dim3(B_), dim3(256), 0, stream>>>(Tbuf, stats, P, flag, v,
                                                               (t == 9) ? out : nullptr);
        }
    }
}

// Round 5
// 731.871 us; speedup vs baseline: 1.5021x; 1.0012x over previous
//
#include <hip/hip_runtime.h>
#include <hip/hip_fp16.h>
#include <hip/hip_cooperative_groups.h>
#include <math.h>

namespace cg = cooperative_groups;

constexpr int B_ = 64;
constexpr int N_ = 4096;
constexpr int D_ = 256;
constexpr int NCH = 64;            // fallback path: chunks per batch row
constexpr int NPB = N_ / NCH;      // 64 rows per block
constexpr int NPW = NPB / 4;       // 16 rows per wave
constexpr int NSTEP = NPW / 4;     // fallback: 4 steps of 4 rows

// ---------------------------------------------------------------------------
// flag: is precision == I?  0 -> fast paths everywhere.
// ---------------------------------------------------------------------------
__global__ __launch_bounds__(256) void flag_kernel(const float* __restrict__ P,
                                                   int* __restrict__ flag) {
    __shared__ int sh[256];
    const int tid = threadIdx.x;
    int bad = 0;
    for (int i = tid; i < D_ * D_; i += 256) {
        const int r = i >> 8, c = i & 255;
        const float expect = (r == c) ? 1.0f : 0.0f;
        bad |= (P[i] != expect) ? 1 : 0;
    }
    sh[tid] = bad;
    __syncthreads();
    for (int s = 128; s > 0; s >>= 1) {
        if (tid < s) sh[tid] |= sh[tid + s];
        __syncthreads();
    }
    if (tid == 0) *flag = sh[0];
}

// ---------------------------------------------------------------------------
// Shared per-row score + online-softmax update. Expects in scope:
// m[4] (row fragment, d = q*8+128*(j>>1)+4*(j&1)+c), vr[4], runM, runS,
// tacc[4], flg, srows, wave, g, q, P.
// ---------------------------------------------------------------------------
#define SCORE_AND_UPDATE()                                                     \
    {                                                                          \
        float p_ = 0.f;                                                        \
        _Pragma("unroll")                                                      \
        for (int j = 0; j < 4; j++) {                                          \
            p_ += m[j].x * (vr[j].x - m[j].x);                                 \
            p_ += m[j].y * (vr[j].y - m[j].y);                                 \
            p_ += m[j].z * (vr[j].z - m[j].z);                                 \
            p_ += m[j].w * (vr[j].w - m[j].w);                                 \
        }                                                                      \
        p_ += __shfl_xor(p_, 1, 64);                                           \
        p_ += __shfl_xor(p_, 2, 64);                                           \
        p_ += __shfl_xor(p_, 4, 64);                                           \
        p_ += __shfl_xor(p_, 8, 64);                                           \
        float s_ = 0.5f * p_;                                                  \
        if (flg) { /* general P: s += 0.5*(||m||^2 - m^T P m) */               \
            __syncthreads();                                                   \
            _Pragma("unroll")                                                  \
            for (int jj = 0; jj < 2; jj++)                                     \
                _Pragma("unroll")                                              \
                for (int h = 0; h < 2; h++)                                    \
                    ((float4*)&srows[wave][g][0])[q * 2 + 32 * jj + h] =       \
                        m[jj * 2 + h];                                         \
            __syncthreads();                                                   \
            float dl = 0.f;                                                    \
            for (int k = 0; k < 16; k++) {                                     \
                const int d_ = q * 16 + k;                                     \
                const float md = srows[wave][g][d_];                           \
                float pm = 0.f;                                                \
                for (int e = 0; e < D_; e++)                                   \
                    pm += P[d_ * D_ + e] * srows[wave][g][e];                  \
                dl += md * (md - pm);                                          \
            }                                                                  \
            dl += __shfl_xor(dl, 1, 64);                                       \
            dl += __shfl_xor(dl, 2, 64);                                       \
            dl += __shfl_xor(dl, 4, 64);                                       \
            dl += __shfl_xor(dl, 8, 64);                                       \
            s_ += 0.5f * dl;                                                   \
        }                                                                      \
        const float newM_ = fmaxf(runM, s_);                                   \
        const float sc_ = __expf(runM - newM_);                                \
        const float e_  = __expf(s_ - newM_);                                  \
        runS = fmaf(runS, sc_, e_);                                            \
        _Pragma("unroll")                                                      \
        for (int j = 0; j < 4; j++) {                                          \
            tacc[j].x = fmaf(tacc[j].x, sc_, e_ * m[j].x);                     \
            tacc[j].y = fmaf(tacc[j].y, sc_, e_ * m[j].y);                     \
            tacc[j].z = fmaf(tacc[j].z, sc_, e_ * m[j].z);                     \
            tacc[j].w = fmaf(tacc[j].w, sc_, e_ * m[j].w);                     \
        }                                                                      \
        runM = newM_;                                                          \
    }

// ---------------------------------------------------------------------------
// Persistent cooperative kernel: all 10 iterations in one launch.
// GRID = 64*PARTS_ blocks; block gid handles rows [part*RPB, +RPB) of batch
// row bb (gid = bb*PARTS_ + part). One grid.sync per iteration; partial
// (M,S,T[256]) buffers double-buffered in workspace.
// ---------------------------------------------------------------------------
template <bool USE_H, int PARTS_>
__global__ __launch_bounds__(256) void persistent_kernel(
        const float* __restrict__ means, const float* __restrict__ z0,
        const float* __restrict__ P, const int* __restrict__ flag,
        __half* __restrict__ mh, float* __restrict__ pT,
        float2* __restrict__ pS, float* __restrict__ out) {
    constexpr int GRID = 64 * PARTS_;
    constexpr int RPB = N_ / PARTS_;   // rows per block
    constexpr int RPW = RPB / 4;       // rows per wave
    constexpr int NSTEPS = RPW / 4;    // 4 rows (one per 16-lane group) per step
    cg::grid_group grid = cg::this_grid();

    const int gid = blockIdx.x, bb = gid / PARTS_, part = gid % PARTS_;
    const int tid = threadIdx.x, wave = tid >> 6, lane = tid & 63;
    const int q = lane & 15, g = lane >> 4;

    __shared__ __align__(16) float vsh[D_];
    __shared__ __align__(16) float shbuf[4][D_];
    __shared__ __align__(16) float srows[4][4][D_];   // slow path only
    __shared__ __align__(16) float zsh[D_];
    __shared__ float wM[4], wS[4];

    const int flg = *flag;

    // v0 = (P+P^T) z0  (fast path 2*z0)
    {
        const float zd = z0[bb * D_ + tid];
        if (!flg) {
            vsh[tid] = 2.f * zd;
        } else {
            zsh[tid] = zd;
            __syncthreads();
            float vv = 0.f;
            for (int e = 0; e < D_; e++)
                vv += (P[tid * D_ + e] + P[e * D_ + tid]) * zsh[e];
            vsh[tid] = vv;
        }
        __syncthreads();
    }

    const size_t wrowbase = (size_t)bb * N_ + (size_t)part * RPB + (size_t)wave * RPW;

    for (int t = 0; t < 10; t++) {
        float4 vr[4];   // vr[jj*2+h] covers d = q*8 + 128*jj + 4*h
        #pragma unroll
        for (int jj = 0; jj < 2; jj++)
            #pragma unroll
            for (int h = 0; h < 2; h++)
                vr[jj * 2 + h] = ((const float4*)vsh)[q * 2 + 32 * jj + h];

        float runM = -INFINITY, runS = 0.f;
        float4 tacc[4];
        #pragma unroll
        for (int j = 0; j < 4; j++) tacc[j] = make_float4(0.f, 0.f, 0.f, 0.f);

        if (USE_H && t > 0) {
            for (int step = 0; step < NSTEPS; step++) {
                const int r = step * 4 + g;
                const __half* rp = mh + (wrowbase + r) * D_;
                float4 m[4];
                #pragma unroll
                for (int jj = 0; jj < 2; jj++) {
                    float4 raw = ((const float4*)rp)[q + 16 * jj];   // 8 halves
                    const __half2* hp2 = (const __half2*)&raw;
                    const float2 f0 = __half22float2(hp2[0]);
                    const float2 f1 = __half22float2(hp2[1]);
                    const float2 f2 = __half22float2(hp2[2]);
                    const float2 f3 = __half22float2(hp2[3]);
                    m[jj * 2 + 0] = make_float4(f0.x, f0.y, f1.x, f1.y);
                    m[jj * 2 + 1] = make_float4(f2.x, f2.y, f3.x, f3.y);
                }
                SCORE_AND_UPDATE()
            }
        } else {
            for (int step = 0; step < NSTEPS; step++) {
                const int r = step * 4 + g;
                const float* rp = means + (wrowbase + r) * D_;
                float4 m[4];
                #pragma unroll
                for (int jj = 0; jj < 2; jj++)
                    #pragma unroll
                    for (int h = 0; h < 2; h++)
                        m[jj * 2 + h] = ((const float4*)rp)[q * 2 + 32 * jj + h];
                if (USE_H && t == 0) {
                    __half* hp = mh + (wrowbase + r) * D_;
                    #pragma unroll
                    for (int jj = 0; jj < 2; jj++) {
                        union { uint4 u4; __half2 h2[4]; } pk;
                        pk.h2[0] = __floats2half2_rn(m[jj*2].x,   m[jj*2].y);
                        pk.h2[1] = __floats2half2_rn(m[jj*2].z,   m[jj*2].w);
                        pk.h2[2] = __floats2half2_rn(m[jj*2+1].x, m[jj*2+1].y);
                        pk.h2[3] = __floats2half2_rn(m[jj*2+1].z, m[jj*2+1].w);
                        *(uint4*)(hp + q * 8 + 128 * jj) = pk.u4;
                    }
                }
                SCORE_AND_UPDATE()
            }
        }

        // ---- epilogue: combine 4 lane-groups (xor 16/32), then 4 waves ----
        float Mw = runM;
        Mw = fmaxf(Mw, __shfl_xor(Mw, 16, 64));
        Mw = fmaxf(Mw, __shfl_xor(Mw, 32, 64));
        const float aw = __expf(runM - Mw);
        float Sa = runS * aw;
        Sa += __shfl_xor(Sa, 16, 64);
        Sa += __shfl_xor(Sa, 32, 64);
        #pragma unroll
        for (int j = 0; j < 4; j++) {
            tacc[j].x *= aw; tacc[j].y *= aw; tacc[j].z *= aw; tacc[j].w *= aw;
            tacc[j].x += __shfl_xor(tacc[j].x, 16, 64);
            tacc[j].y += __shfl_xor(tacc[j].y, 16, 64);
            tacc[j].z += __shfl_xor(tacc[j].z, 16, 64);
            tacc[j].w += __shfl_xor(tacc[j].w, 16, 64);
            tacc[j].x += __shfl_xor(tacc[j].x, 32, 64);
            tacc[j].y += __shfl_xor(tacc[j].y, 32, 64);
            tacc[j].z += __shfl_xor(tacc[j].z, 32, 64);
            tacc[j].w += __shfl_xor(tacc[j].w, 32, 64);
        }
        if (lane < 16) {
            #pragma unroll
            for (int j = 0; j < 4; j++)
                ((float4*)shbuf[wave])[q * 2 + 32 * (j >> 1) + (j & 1)] = tacc[j];
        }
        if (lane == 0) { wM[wave] = Mw; wS[wave] = Sa; }
        __syncthreads();
        const float Mb = fmaxf(fmaxf(wM[0], wM[1]), fmaxf(wM[2], wM[3]));
        const float a0 = __expf(wM[0] - Mb), a1 = __expf(wM[1] - Mb),
                    a2 = __expf(wM[2] - Mb), a3 = __expf(wM[3] - Mb);
        const float Tc = a0 * shbuf[0][tid] + a1 * shbuf[1][tid] +
                         a2 * shbuf[2][tid] + a3 * shbuf[3][tid];
        const int buf = t & 1;
        pT[((size_t)buf * GRID + gid) * D_ + tid] = Tc;
        if (tid == 0)
            pS[buf * GRID + gid] = make_float2(
                Mb, a0 * wS[0] + a1 * wS[1] + a2 * wS[2] + a3 * wS[3]);

        grid.sync();

        // ---- combine PARTS_ partials for my bb (redundant per part) ----
        float Mg = -INFINITY;
        float2 stl[PARTS_];
        #pragma unroll
        for (int pI = 0; pI < PARTS_; pI++) {
            stl[pI] = pS[buf * GRID + bb * PARTS_ + pI];
            Mg = fmaxf(Mg, stl[pI].x);
        }
        float Sg = 0.f, accg = 0.f;
        #pragma unroll
        for (int pI = 0; pI < PARTS_; pI++) {
            const float a = __expf(stl[pI].x - Mg);
            Sg += a * stl[pI].y;
            accg += a * pT[((size_t)buf * GRID + bb * PARTS_ + pI) * D_ + tid];
        }
        const float zv = accg / Sg;
        if (t == 9) {
            if (part == 0) out[bb * D_ + tid] = zv;
        } else {
            if (!flg) {
                vsh[tid] = 2.f * zv;
            } else {
                zsh[tid] = zv;
                __syncthreads();
                float vv = 0.f;
                for (int e = 0; e < D_; e++)
                    vv += (P[tid * D_ + e] + P[e * D_ + tid]) * zsh[e];
                vsh[tid] = vv;
            }
            __syncthreads();
        }
    }
}

// ===========================================================================
// Fallback multi-kernel path (round-4, proven) — used if workspace or
// cooperative occupancy is insufficient.
// ===========================================================================
__global__ __launch_bounds__(256) void vcalc_kernel(const float* __restrict__ P,
                                                    const float* __restrict__ z,
                                                    const int* __restrict__ flag,
                                                    float* __restrict__ v) {
    __shared__ float zsh[D_];
    const int b = blockIdx.x, d = threadIdx.x;
    const float zd = z[b * D_ + d];
    if (*flag == 0) {
        v[b * D_ + d] = 2.0f * zd;
        return;
    }
    zsh[d] = zd;
    __syncthreads();
    float acc = 0.f;
    for (int e = 0; e < D_; e++)
        acc += (P[d * D_ + e] + P[e * D_ + d]) * zsh[e];
    v[b * D_ + d] = acc;
}

template <bool WRITE_H>
__global__ __launch_bounds__(256) void fused_f32_kernel(const float* __restrict__ means,
                                                        const float* __restrict__ v,
                                                        const float* __restrict__ P,
                                                        const int* __restrict__ flag,
                                                        __half* __restrict__ mh,
                                                        float* __restrict__ Tbuf,
                                                        float2* __restrict__ stats) {
    const int b = blockIdx.y, chunk = blockIdx.x;
    const int tid = threadIdx.x, wave = tid >> 6, lane = tid & 63;
    const int q = lane & 15, g = lane >> 4;
    __shared__ __align__(16) float vsh[D_];
    __shared__ __align__(16) float shbuf[4][D_];
    __shared__ __align__(16) float srows[4][4][D_];
    __shared__ float wM[4], wS[4];
    vsh[tid] = v[b * D_ + tid];
    __syncthreads();
    float4 vr[4];
    #pragma unroll
    for (int jj = 0; jj < 2; jj++)
        #pragma unroll
        for (int h = 0; h < 2; h++)
            vr[jj * 2 + h] = ((const float4*)vsh)[q * 2 + 32 * jj + h];
    const int flg = *flag;

    float runM = -INFINITY, runS = 0.f;
    float4 tacc[4];
    #pragma unroll
    for (int j = 0; j < 4; j++) tacc[j] = make_float4(0.f, 0.f, 0.f, 0.f);

    const size_t rowbase = (size_t)b * N_ + (size_t)chunk * NPB + (size_t)wave * NPW;

    for (int step = 0; step < NSTEP; step++) {
        const int r = step * 4 + g;
        const float* rp = means + (rowbase + r) * D_;
        float4 m[4];
        #pragma unroll
        for (int jj = 0; jj < 2; jj++)
            #pragma unroll
            for (int h = 0; h < 2; h++)
                m[jj * 2 + h] = ((const float4*)rp)[q * 2 + 32 * jj + h];
        if (WRITE_H) {
            __half* hp = mh + (rowbase + r) * D_;
            #pragma unroll
            for (int jj = 0; jj < 2; jj++) {
                union { uint4 u4; __half2 h2[4]; } pk;
                pk.h2[0] = __floats2half2_rn(m[jj*2].x,   m[jj*2].y);
                pk.h2[1] = __floats2half2_rn(m[jj*2].z,   m[jj*2].w);
                pk.h2[2] = __floats2half2_rn(m[jj*2+1].x, m[jj*2+1].y);
                pk.h2[3] = __floats2half2_rn(m[jj*2+1].z, m[jj*2+1].w);
                *(uint4*)(hp + q * 8 + 128 * jj) = pk.u4;
            }
        }
        SCORE_AND_UPDATE()
    }

    float Mw = runM;
    Mw = fmaxf(Mw, __shfl_xor(Mw, 16, 64));
    Mw = fmaxf(Mw, __shfl_xor(Mw, 32, 64));
    const float aw = __expf(runM - Mw);
    float Sa = runS * aw;
    Sa += __shfl_xor(Sa, 16, 64);
    Sa += __shfl_xor(Sa, 32, 64);
    #pragma unroll
    for (int j = 0; j < 4; j++) {
        tacc[j].x *= aw; tacc[j].y *= aw; tacc[j].z *= aw; tacc[j].w *= aw;
        tacc[j].x += __shfl_xor(tacc[j].x, 16, 64);
        tacc[j].y += __shfl_xor(tacc[j].y, 16, 64);
        tacc[j].z += __shfl_xor(tacc[j].z, 16, 64);
        tacc[j].w += __shfl_xor(tacc[j].w, 16, 64);
        tacc[j].x += __shfl_xor(tacc[j].x, 32, 64);
        tacc[j].y += __shfl_xor(tacc[j].y, 32, 64);
        tacc[j].z += __shfl_xor(tacc[j].z, 32, 64);
        tacc[j].w += __shfl_xor(tacc[j].w, 32, 64);
    }
    if (lane < 16) {
        #pragma unroll
        for (int j = 0; j < 4; j++)
            ((float4*)shbuf[wave])[q * 2 + 32 * (j >> 1) + (j & 1)] = tacc[j];
    }
    if (lane == 0) { wM[wave] = Mw; wS[wave] = Sa; }
    __syncthreads();
    const float Mb = fmaxf(fmaxf(wM[0], wM[1]), fmaxf(wM[2], wM[3]));
    const float a0 = __expf(wM[0] - Mb), a1 = __expf(wM[1] - Mb),
                a2 = __expf(wM[2] - Mb), a3 = __expf(wM[3] - Mb);
    const float Tc = a0 * shbuf[0][tid] + a1 * shbuf[1][tid] +
                     a2 * shbuf[2][tid] + a3 * shbuf[3][tid];
    Tbuf[((size_t)(b * NCH + chunk)) * D_ + tid] = Tc;
    if (tid == 0)
        stats[b * NCH + chunk] = make_float2(
            Mb, a0 * wS[0] + a1 * wS[1] + a2 * wS[2] + a3 * wS[3]);
}

__global__ __launch_bounds__(256) void fused_f16_kernel(const __half* __restrict__ mh,
                                                        const float* __restrict__ v,
                                                        const float* __restrict__ P,
                                                        const int* __restrict__ flag,
                                                        float* __restrict__ Tbuf,
                                                        float2* __restrict__ stats) {
    const int b = blockIdx.y, chunk = blockIdx.x;
    const int tid = threadIdx.x, wave = tid >> 6, lane = tid & 63;
    const int q = lane & 15, g = lane >> 4;
    __shared__ __align__(16) float vsh[D_];
    __shared__ __align__(16) float shbuf[4][D_];
    __shared__ __align__(16) float srows[4][4][D_];
    __shared__ float wM[4], wS[4];
    vsh[tid] = v[b * D_ + tid];
    __syncthreads();
    float4 vr[4];
    #pragma unroll
    for (int jj = 0; jj < 2; jj++)
        #pragma unroll
        for (int h = 0; h < 2; h++)
            vr[jj * 2 + h] = ((const float4*)vsh)[q * 2 + 32 * jj + h];
    const int flg = *flag;

    float runM = -INFINITY, runS = 0.f;
    float4 tacc[4];
    #pragma unroll
    for (int j = 0; j < 4; j++) tacc[j] = make_float4(0.f, 0.f, 0.f, 0.f);

    const size_t rowbase = (size_t)b * N_ + (size_t)chunk * NPB + (size_t)wave * NPW;

    for (int step = 0; step < NSTEP; step++) {
        const int r = step * 4 + g;
        const __half* rp = mh + (rowbase + r) * D_;
        float4 m[4];
        #pragma unroll
        for (int jj = 0; jj < 2; jj++) {
            float4 raw = ((const float4*)rp)[q + 16 * jj];
            const __half2* hp2 = (const __half2*)&raw;
            const float2 f0 = __half22float2(hp2[0]);
            const float2 f1 = __half22float2(hp2[1]);
            const float2 f2 = __half22float2(hp2[2]);
            const float2 f3 = __half22float2(hp2[3]);
            m[jj * 2 + 0] = make_float4(f0.x, f0.y, f1.x, f1.y);
            m[jj * 2 + 1] = make_float4(f2.x, f2.y, f3.x, f3.y);
        }
        SCORE_AND_UPDATE()
    }

    float Mw = runM;
    Mw = fmaxf(Mw, __shfl_xor(Mw, 16, 64));
    Mw = fmaxf(Mw, __shfl_xor(Mw, 32, 64));
    const float aw = __expf(runM - Mw);
    float Sa = runS * aw;
    Sa += __shfl_xor(Sa, 16, 64);
    Sa += __shfl_xor(Sa, 32, 64);
    #pragma unroll
    for (int j = 0; j < 4; j++) {
        tacc[j].x *= aw; tacc[j].y *= aw; tacc[j].z *= aw; tacc[j].w *= aw;
        tacc[j].x += __shfl_xor(tacc[j].x, 16, 64);
        tacc[j].y += __shfl_xor(tacc[j].y, 16, 64);
        tacc[j].z += __shfl_xor(tacc[j].z, 16, 64);
        tacc[j].w += __shfl_xor(tacc[j].w, 16, 64);
        tacc[j].x += __shfl_xor(tacc[j].x, 32, 64);
        tacc[j].y += __shfl_xor(tacc[j].y, 32, 64);
        tacc[j].z += __shfl_xor(tacc[j].z, 32, 64);
        tacc[j].w += __shfl_xor(tacc[j].w, 32, 64);
    }
    if (lane < 16) {
        #pragma unroll
        for (int j = 0; j < 4; j++)
            ((float4*)shbuf[wave])[q * 2 + 32 * (j >> 1) + (j & 1)] = tacc[j];
    }
    if (lane == 0) { wM[wave] = Mw; wS[wave] = Sa; }
    __syncthreads();
    const float Mb = fmaxf(fmaxf(wM[0], wM[1]), fmaxf(wM[2], wM[3]));
    const float a0 = __expf(wM[0] - Mb), a1 = __expf(wM[1] - Mb),
                a2 = __expf(wM[2] - Mb), a3 = __expf(wM[3] - Mb);
    const float Tc = a0 * shbuf[0][tid] + a1 * shbuf[1][tid] +
                     a2 * shbuf[2][tid] + a3 * shbuf[3][tid];
    Tbuf[((size_t)(b * NCH + chunk)) * D_ + tid] = Tc;
    if (tid == 0)
        stats[b * NCH + chunk] = make_float2(
            Mb, a0 * wS[0] + a1 * wS[1] + a2 * wS[2] + a3 * wS[3]);
}

__global__ __launch_bounds__(256) void combine_kernel(const float* __restrict__ Tbuf,
                                                      const float2* __restrict__ stats,
                                                      const float* __restrict__ P,
                                                      const int* __restrict__ flag,
                                                      float* __restrict__ v,
                                                      float* __restrict__ out) {
    const int b = blockIdx.x, d = threadIdx.x;
    __shared__ float Msh[NCH], Ssh[NCH];
    __shared__ float zsh[D_];
    if (d < NCH) {
        const float2 st = stats[b * NCH + d];
        Msh[d] = st.x; Ssh[d] = st.y;
    }
    __syncthreads();
    float M = -INFINITY;
    for (int c = 0; c < NCH; c++) M = fmaxf(M, Msh[c]);
    float S = 0.f, acc = 0.f;
    for (int c = 0; c < NCH; c++) {
        const float a = __expf(Msh[c] - M);
        S += a * Ssh[c];
        acc += a * Tbuf[((size_t)(b * NCH + c)) * D_ + d];
    }
    const float z = acc / S;
    if (out) out[b * D_ + d] = z;
    if (*flag == 0) {
        v[b * D_ + d] = 2.0f * z;
        return;
    }
    zsh[d] = z;
    __syncthreads();
    float vv = 0.f;
    for (int e = 0; e < D_; e++)
        vv += (P[d * D_ + e] + P[e * D_ + d]) * zsh[e];
    v[b * D_ + d] = vv;
}

extern "C" void kernel_launch(void* const* d_in, const int* in_sizes, int n_in,
                              void* d_out, int out_size, void* d_ws, size_t ws_size,
                              hipStream_t stream) {
    // inputs: 0=x (unused), 1=z, 2=means, 3=precision, 4=iterations(=10)
    const float* z0    = (const float*)d_in[1];
    const float* means = (const float*)d_in[2];
    const float* P     = (const float*)d_in[3];
    float* out = (float*)d_out;

    char* ws = (char*)d_ws;
    size_t off = 0;
    int*    flag  = (int*)ws;                     off = 256;
    float*  v     = (float*)(ws + off);           off += (size_t)B_ * D_ * 4;
    float*  Tbuf  = (float*)(ws + off);           off += (size_t)B_ * NCH * D_ * 4;
    float2* stats = (float2*)(ws + off);          off += (size_t)B_ * NCH * 8;
    off = (off + 255) & ~(size_t)255;
    float*  pT    = (float*)(ws + off);           off += 2ull * 1024 * D_ * 4;
    float2* pS    = (float2*)(ws + off);          off += 2ull * 1024 * 8;
    off = (off + 255) & ~(size_t)255;
    __half* mh    = (__half*)(ws + off);
    const size_t coop_need  = off;                               // ~6.3 MiB
    const size_t full_need  = off + (size_t)B_ * N_ * D_ * 2;    // + 128 MiB
    const bool use_h = (ws_size >= full_need);
    const bool ws_ok = (ws_size >= coop_need);

    flag_kernel<<<dim3(1), dim3(256), 0, stream>>>(P, flag);

    // ---- cooperative persistent path (preferred) ----
    if (ws_ok) {
        void* args[] = {(void*)&means, (void*)&z0, (void*)&P, (void*)&flag,
                        (void*)&mh, (void*)&pT, (void*)&pS, (void*)&out};
        int nb = 0;
        if (use_h) {
            if (hipOccupancyMaxActiveBlocksPerMultiprocessor(
                    &nb, persistent_kernel<true, 16>, 256, 0) == hipSuccess && nb >= 4) {
                if (hipLaunchCooperativeKernel(persistent_kernel<true, 16>,
                        dim3(1024), dim3(256), args, 0, stream) == hipSuccess)
                    return;
            }
            nb = 0;
            if (hipOccupancyMaxActiveBlocksPerMultiprocessor(
                    &nb, persistent_kernel<true, 8>, 256, 0) == hipSuccess && nb >= 2) {
                if (hipLaunchCooperativeKernel(persistent_kernel<true, 8>,
                        dim3(512), dim3(256), args, 0, stream) == hipSuccess)
                    return;
            }
        } else {
            if (hipOccupancyMaxActiveBlocksPerMultiprocessor(
                    &nb, persistent_kernel<false, 16>, 256, 0) == hipSuccess && nb >= 4) {
                if (hipLaunchCooperativeKernel(persistent_kernel<false, 16>,
                        dim3(1024), dim3(256), args, 0, stream) == hipSuccess)
                    return;
            }
            nb = 0;
            if (hipOccupancyMaxActiveBlocksPerMultiprocessor(
                    &nb, persistent_kernel<false, 8>, 256, 0) == hipSuccess && nb >= 2) {
                if (hipLaunchCooperativeKernel(persistent_kernel<false, 8>,
                        dim3(512), dim3(256), args, 0, stream) == hipSuccess)
                    return;
            }
        }
    }

    // ---- fallback multi-kernel path (round-4) ----
    vcalc_kernel<<<dim3(B_), dim3(256), 0, stream>>>(P, z0, flag, v);
    if (use_h) {
        fused_f32_kernel<true><<<dim3(NCH, B_), dim3(256), 0, stream>>>(
            means, v, P, flag, mh, Tbuf, stats);
        combine_kernel<<<dim3(B_), dim3(256), 0, stream>>>(Tbuf, stats, P, flag, v, nullptr);
        for (int t = 1; t < 10; t++) {
            fused_f16_kernel<<<dim3(NCH, B_), dim3(256), 0, stream>>>(
                mh, v, P, flag, Tbuf, stats);
            combine_kernel<<<dim3(B_), dim3(256), 0, stream>>>(Tbuf, stats, P, flag, v,
                                                               (t == 9) ? out : nullptr);
        }
    } else {
        for (int t = 0; t < 10; t++) {
            fused_f32_kernel<false><<<dim3(NCH, B_), dim3(256), 0, stream>>>(
                means, v, P, flag, nullptr, Tbuf, stats);
            combine_kernel<<<dim3(B_), dim3(256), 0, stream>>>(Tbuf, stats, P, flag, v,
                                                               (t == 9) ? out : nullptr);
        }
    }
}